// Round 3
// baseline (212.573 us; speedup 1.0000x reference)
//
#include <hip/hip_runtime.h>

typedef unsigned int u32;

#define NPIX 524288
#define DH 22
#define NHID 11   // hidden layers after layer 0

__device__ __forceinline__ void activate(float* h) {
#pragma unroll
    for (int j = 15; j < 19; ++j) h[j] = __expf(-h[j]*h[j]) * 2.0f - 1.0f;
    h[21] = __sinf(h[21]);
}

__device__ __forceinline__ void store_h22(float* dst, const float* h) {
    // byte base = 28N + 88N*l + 88p -> always 8B aligned; use float2 stores
    float2* d2 = (float2*)dst;
#pragma unroll
    for (int k = 0; k < 11; ++k)
        d2[k] = make_float2(h[2*k], h[2*k+1]);
}

__global__ __launch_bounds__(256) void cppn_main(const float* __restrict__ xin,
                                                 const float* __restrict__ Win,
                                                 const float* __restrict__ Whid,
                                                 const float* __restrict__ Wout,
                                                 float* __restrict__ out) {
    const int p = blockIdx.x * 256 + threadIdx.x;

    // ---- load x: 4 fp32, vectorized ----
    const float4 xv = ((const float4*)xin)[p];

    // ---- layer 0: x[4] @ w_in[4,22] (weights wave-uniform -> s_load) ----
    float h[DH];
#pragma unroll
    for (int o = 0; o < DH; ++o) {
        float a =      xv.x * Win[0*DH + o];
        a = fmaf(xv.y, Win[1*DH + o], a);
        a = fmaf(xv.z, Win[2*DH + o], a);
        a = fmaf(xv.w, Win[3*DH + o], a);
        h[o] = a;
    }
    activate(h);

    // ---- tuple layout (fp32 elems): out[3N] | x[4N] | h0..h11 [22N each] | out[3N] ----
    // x chunk: elem 3N + 4p -> byte 12N + 16p, 16B aligned
    ((float4*)(out + (size_t)3 * NPIX))[p] = xv;

    float* hbase = out + (size_t)7 * NPIX;
    store_h22(hbase + (size_t)p * DH, h);

    // ---- hidden layers: h = act(h @ W[l]) ----
    const float* Wl = Whid;
    for (int l = 0; l < NHID; ++l) {
        float hn[DH];
#pragma unroll
        for (int o = 0; o < DH; ++o) hn[o] = 0.0f;
#pragma unroll
        for (int i = 0; i < DH; ++i) {
            float hi = h[i];
#pragma unroll
            for (int o = 0; o < DH; ++o)
                hn[o] = fmaf(hi, Wl[i*DH + o], hn[o]);
        }
        activate(hn);
#pragma unroll
        for (int o = 0; o < DH; ++o) h[o] = hn[o];
        store_h22(hbase + (size_t)(l + 1) * NPIX * DH + (size_t)p * DH, h);
        Wl += DH * DH;
    }

    // ---- output projection: h[22] @ w_out[22,3] ----
    float o0 = 0.0f, o1 = 0.0f, o2 = 0.0f;
#pragma unroll
    for (int d = 0; d < DH; ++d) {
        o0 = fmaf(h[d], Wout[d*3 + 0], o0);
        o1 = fmaf(h[d], Wout[d*3 + 1], o1);
        o2 = fmaf(h[d], Wout[d*3 + 2], o2);
    }
    float* op0 = out + (size_t)p * 3;                      // first tuple element
    op0[0] = o0; op0[1] = o1; op0[2] = o2;
    float* op1 = out + (size_t)271 * NPIX + (size_t)p * 3; // last tuple element
    op1[0] = o0; op1[1] = o1; op1[2] = o2;
}

extern "C" void kernel_launch(void* const* d_in, const int* in_sizes, int n_in,
                              void* d_out, int out_size, void* d_ws, size_t ws_size,
                              hipStream_t stream) {
    const float* x     = (const float*)d_in[0];
    const float* w_in  = (const float*)d_in[1];
    const float* w_hid = (const float*)d_in[2];
    const float* w_out = (const float*)d_in[3];
    float* o = (float*)d_out;

    cppn_main<<<NPIX / 256, 256, 0, stream>>>(x, w_in, w_hid, w_out, o);
}

// Round 4
// 147.327 us; speedup vs baseline: 1.4429x; 1.4429x over previous
//
#include <hip/hip_runtime.h>

#define NPIX 524288
#define DH 22
#define NHID 11      // hidden layers after layer 0
#define TPB 256
#define LROW 23      // padded LDS row stride (odd -> conflict-free writes)

__device__ __forceinline__ void activate(float* h) {
#pragma unroll
    for (int j = 15; j < 19; ++j) h[j] = __expf(-h[j]*h[j]) * 2.0f - 1.0f;
    h[21] = __sinf(h[21]);
}

// Stage this block's [256 x 22] tile in LDS, then store fully coalesced.
__device__ __forceinline__ void flush_h(float* __restrict__ gbase, const float* h,
                                        int t, float* __restrict__ lds) {
    __syncthreads();                       // previous tile's reads complete
#pragma unroll
    for (int j = 0; j < DH; ++j) lds[t * LROW + j] = h[j];
    __syncthreads();
    // float2 slot s = t + 256k, k=0..10  (2816 slots = 5632 floats)
    // L = 2s is even and 22 is even -> the pair never crosses a pixel row.
#pragma unroll
    for (int k = 0; k < 11; ++k) {
        const int s  = t + TPB * k;
        const int pp = s / 11;             // pixel within tile (magic-mul)
        const int r  = s - pp * 11;
        const float a = lds[pp * LROW + 2*r];
        const float b = lds[pp * LROW + 2*r + 1];
        ((float2*)gbase)[s] = make_float2(a, b);
    }
}

__global__ __launch_bounds__(256) void cppn_main(const float* __restrict__ xin,
                                                 const float* __restrict__ Win,
                                                 const float* __restrict__ Whid,
                                                 const float* __restrict__ Wout,
                                                 float* __restrict__ out) {
    __shared__ float lds[TPB * LROW];
    const int t   = threadIdx.x;
    const int blk = blockIdx.x;
    const int p   = blk * TPB + t;

    // ---- load x: 4 fp32 vectorized ----
    const float4 xv = ((const float4*)xin)[p];

    // ---- layer 0: x[4] @ w_in[4,22] (wave-uniform weights -> s_load) ----
    float h[DH];
#pragma unroll
    for (int o = 0; o < DH; ++o) {
        float a =      xv.x * Win[0*DH + o];
        a = fmaf(xv.y, Win[1*DH + o], a);
        a = fmaf(xv.z, Win[2*DH + o], a);
        a = fmaf(xv.w, Win[3*DH + o], a);
        h[o] = a;
    }
    activate(h);

    // ---- tuple layout (fp32): out[3N] | x[4N] | h0..h11 [22N each] | out[3N] ----
    ((float4*)(out + (size_t)3 * NPIX))[p] = xv;   // x chunk, coalesced

    float* hbase = out + (size_t)7 * NPIX + (size_t)blk * (TPB * DH);
    flush_h(hbase, h, t, lds);

    // ---- hidden layers: h = act(h @ W[l]) ----
    const float* Wl = Whid;
    for (int l = 0; l < NHID; ++l) {
        float hn[DH];
#pragma unroll
        for (int o = 0; o < DH; ++o) hn[o] = 0.0f;
#pragma unroll
        for (int i = 0; i < DH; ++i) {
            const float hi = h[i];
#pragma unroll
            for (int o = 0; o < DH; ++o)
                hn[o] = fmaf(hi, Wl[i*DH + o], hn[o]);
        }
        activate(hn);
#pragma unroll
        for (int o = 0; o < DH; ++o) h[o] = hn[o];
        flush_h(hbase + (size_t)(l + 1) * NPIX * DH, h, t, lds);
        Wl += DH * DH;
    }

    // ---- output projection: h[22] @ w_out[22,3] ----
    float o0 = 0.0f, o1 = 0.0f, o2 = 0.0f;
#pragma unroll
    for (int d = 0; d < DH; ++d) {
        o0 = fmaf(h[d], Wout[d*3 + 0], o0);
        o1 = fmaf(h[d], Wout[d*3 + 1], o1);
        o2 = fmaf(h[d], Wout[d*3 + 2], o2);
    }
    // stage [256 x 3] tile, store coalesced to BOTH out chunks
    __syncthreads();                       // last h-tile reads complete
    lds[t*3 + 0] = o0; lds[t*3 + 1] = o1; lds[t*3 + 2] = o2;  // stride 3: conflict-free
    __syncthreads();
    float* g0 = out + (size_t)blk * (TPB * 3);
    float* g1 = out + (size_t)271 * NPIX + (size_t)blk * (TPB * 3);
#pragma unroll
    for (int k = 0; k < 3; ++k) {
        const int s = t + TPB * k;         // linear: lds row stride 3 == global layout
        const float v = lds[s];
        g0[s] = v;
        g1[s] = v;
    }
}

extern "C" void kernel_launch(void* const* d_in, const int* in_sizes, int n_in,
                              void* d_out, int out_size, void* d_ws, size_t ws_size,
                              hipStream_t stream) {
    const float* x     = (const float*)d_in[0];
    const float* w_in  = (const float*)d_in[1];
    const float* w_hid = (const float*)d_in[2];
    const float* w_out = (const float*)d_in[3];
    float* o = (float*)d_out;

    cppn_main<<<NPIX / TPB, TPB, 0, stream>>>(x, w_in, w_hid, w_out, o);
}